// Round 4
// baseline (30.977 us; speedup 1.0000x reference)
//
#include <hip/hip_runtime.h>
#include <math.h>

#define KCL 64
#define NPTS 32768
#define NBATCH 8
#define BLOCK 256
#define PPT 2
#define PTS_PER_BLOCK (BLOCK * PPT)                  // 512
#define NBLOCKS (NBATCH * NPTS / PTS_PER_BLOCK)      // 512
#define BLOCKS_PER_B (NPTS / PTS_PER_BLOCK)          // 64

// ws layout (floats): [0 .. 8191] records (512 x 16f = 32KB)
//                     [8192 .. 8703] block partials (512 f)
//                     [8704] ticket counter (uint)
#define WS_REC 0
#define WS_PART 8192
#define WS_CNT 8704

// ---------------------------------------------------------------------------
// Fold kernel: 1 block x 512 threads. Record per (b,k), float4 layout:
//   [m00 m01 m02 m10][m11 m12 m20 m21][m22 q0 q1 q2][const 0 0 0]
// M = diag(sqrt(0.5*log2 e)/s) * R^T, q = M*center ->
//   weight = const * exp2(-|M p - q|^2).
// Thread 0 zeroes the ticket counter for the main kernel.
// ---------------------------------------------------------------------------
__global__ __launch_bounds__(NBATCH * KCL) void fold_params_kernel(
    const float* __restrict__ constants,
    const float* __restrict__ scales,
    const float* __restrict__ rotations,
    const float* __restrict__ centers,
    float*       __restrict__ ws)
{
    const int t = threadIdx.x;            // b*64 + k
    if (t == 0) ((unsigned int*)ws)[WS_CNT] = 0u;

    const float rx = rotations[3 * t + 0];
    const float ry = rotations[3 * t + 1];
    const float rz = rotations[3 * t + 2];
    const float sx = sinf(rx), cx = cosf(rx);
    const float sy = sinf(ry), cy = cosf(ry);
    const float sz = sinf(rz), cz = cosf(rz);

    float R[3][3];
    R[0][0] = cz * cy; R[0][1] = cz * sy * sx - sz * cx; R[0][2] = cz * sy * cx + sz * sx;
    R[1][0] = sz * cy; R[1][1] = sz * sy * sx + cz * cx; R[1][2] = sz * sy * cx - cz * sx;
    R[2][0] = -sy;     R[2][1] = cy * sx;                R[2][2] = cy * cx;

    const float SC = 0.84932184f;  // sqrt(0.5 * log2(e))
    const float inv[3] = { SC / scales[3 * t + 0],
                           SC / scales[3 * t + 1],
                           SC / scales[3 * t + 2] };
    const float c0 = centers[3 * t + 0];
    const float c1 = centers[3 * t + 1];
    const float c2 = centers[3 * t + 2];

    float rec[12];
    #pragma unroll
    for (int i = 0; i < 3; ++i) {
        const float m0 = R[0][i] * inv[i];
        const float m1 = R[1][i] * inv[i];
        const float m2 = R[2][i] * inv[i];
        rec[i * 3 + 0] = m0;
        rec[i * 3 + 1] = m1;
        rec[i * 3 + 2] = m2;
        rec[9 + i] = m0 * c0 + m1 * c1 + m2 * c2;
    }

    float4* r4 = (float4*)(ws + WS_REC) + t * 4;
    r4[0] = make_float4(rec[0], rec[1], rec[2], rec[3]);
    r4[1] = make_float4(rec[4], rec[5], rec[6], rec[7]);
    r4[2] = make_float4(rec[8], rec[9], rec[10], rec[11]);
    r4[3] = make_float4(constants[t], 0.0f, 0.0f, 0.0f);
}

// ---------------------------------------------------------------------------
// Main kernel: P=2 points/thread vs 64 clusters. Records read with
// wave-uniform addresses -> scalar loads (SMEM pipe), inner loop pure VALU.
// Block partials to ws; last block (ticket) reduces and writes the scalar.
// ---------------------------------------------------------------------------
__global__ __launch_bounds__(BLOCK) void point_loss_kernel(
    const float4* __restrict__ pts,
    const float4* __restrict__ recs,   // ws + WS_REC, B*K*4 float4
    float*        __restrict__ partials,
    unsigned int* __restrict__ counter,
    float*        __restrict__ out)
{
    __shared__ float wave_sums[BLOCK / 64];
    __shared__ int is_last;

    const int tid = threadIdx.x;
    const int b   = blockIdx.x / BLOCKS_PER_B;
    const int n0  = (blockIdx.x % BLOCKS_PER_B) * PTS_PER_BLOCK + tid;

    const float4 p0 = pts[b * NPTS + n0];
    const float4 p1 = pts[b * NPTS + n0 + BLOCK];
    const float4* cb = recs + (b * KCL * 4);

    float sdf0 = 0.0f, sdf1 = 0.0f;
    #pragma unroll 4
    for (int k = 0; k < KCL; ++k) {
        const float4 A  = cb[4 * k + 0];
        const float4 Bv = cb[4 * k + 1];
        const float4 C  = cb[4 * k + 2];
        const float cst = cb[4 * k + 3].x;

        float vx = fmaf(A.x, p0.x, fmaf(A.y, p0.y, fmaf(A.z, p0.z, -C.y)));
        float vy = fmaf(A.w, p0.x, fmaf(Bv.x, p0.y, fmaf(Bv.y, p0.z, -C.z)));
        float vz = fmaf(Bv.z, p0.x, fmaf(Bv.w, p0.y, fmaf(C.x, p0.z, -C.w)));
        float d2 = fmaf(vx, vx, fmaf(vy, vy, vz * vz));
        sdf0 = fmaf(cst, __builtin_amdgcn_exp2f(-d2), sdf0);

        vx = fmaf(A.x, p1.x, fmaf(A.y, p1.y, fmaf(A.z, p1.z, -C.y)));
        vy = fmaf(A.w, p1.x, fmaf(Bv.x, p1.y, fmaf(Bv.y, p1.z, -C.z)));
        vz = fmaf(Bv.z, p1.x, fmaf(Bv.w, p1.y, fmaf(C.x, p1.z, -C.w)));
        d2 = fmaf(vx, vx, fmaf(vy, vy, vz * vz));
        sdf1 = fmaf(cst, __builtin_amdgcn_exp2f(-d2), sdf1);
    }

    const float gt0 = (p0.w > 0.0f) ? 1.0f : 0.0f;
    const float z0  = 100.0f * (sdf0 + 0.07f);
    const float pr0 = 1.0f / (1.0f + __builtin_amdgcn_exp2f(-1.44269504f * z0));
    const float w0  = gt0 + 10.0f * (1.0f - gt0);
    const float d0  = gt0 - pr0;

    const float gt1 = (p1.w > 0.0f) ? 1.0f : 0.0f;
    const float z1  = 100.0f * (sdf1 + 0.07f);
    const float pr1 = 1.0f / (1.0f + __builtin_amdgcn_exp2f(-1.44269504f * z1));
    const float w1  = gt1 + 10.0f * (1.0f - gt1);
    const float d1  = gt1 - pr1;

    float term = w0 * d0 * d0 + w1 * d1 * d1;

    #pragma unroll
    for (int off = 32; off > 0; off >>= 1)
        term += __shfl_down(term, off, 64);

    if ((tid & 63) == 0) wave_sums[tid >> 6] = term;
    __syncthreads();

    if (tid == 0) {
        float s = 0.0f;
        #pragma unroll
        for (int i = 0; i < BLOCK / 64; ++i) s += wave_sums[i];
        partials[blockIdx.x] = s;
        __threadfence();                               // release partial
        const unsigned int old = atomicAdd(counter, 1u);
        is_last = (old == NBLOCKS - 1) ? 1 : 0;
    }
    __syncthreads();

    if (is_last) {
        __threadfence();                               // acquire partials
        float s = partials[tid] + partials[tid + 256];
        #pragma unroll
        for (int off = 32; off > 0; off >>= 1)
            s += __shfl_down(s, off, 64);
        if ((tid & 63) == 0) wave_sums[tid >> 6] = s;
        __syncthreads();
        if (tid == 0) {
            float t = wave_sums[0] + wave_sums[1] + wave_sums[2] + wave_sums[3];
            out[0] = t * (1.0f / (NBATCH * (float)NPTS));
        }
    }
}

extern "C" void kernel_launch(void* const* d_in, const int* in_sizes, int n_in,
                              void* d_out, int out_size, void* d_ws, size_t ws_size,
                              hipStream_t stream) {
    const float4* pts       = (const float4*)d_in[0];
    const float*  constants = (const float*)d_in[1];
    const float*  scales    = (const float*)d_in[2];
    const float*  rotations = (const float*)d_in[3];
    const float*  centers   = (const float*)d_in[4];
    float* out = (float*)d_out;
    float* ws  = (float*)d_ws;

    fold_params_kernel<<<1, NBATCH * KCL, 0, stream>>>(
        constants, scales, rotations, centers, ws);

    point_loss_kernel<<<NBLOCKS, BLOCK, 0, stream>>>(
        pts, (const float4*)(ws + WS_REC), ws + WS_PART,
        (unsigned int*)(ws + WS_CNT), out);
}

// Round 5
// 22.132 us; speedup vs baseline: 1.3997x; 1.3997x over previous
//
#include <hip/hip_runtime.h>
#include <math.h>

#define KCL 64
#define NPTS 32768
#define NBATCH 8
#define BLOCK 256
#define PPT 2
#define PTS_PER_BLOCK (BLOCK * PPT)                  // 512
#define NBLOCKS (NBATCH * NPTS / PTS_PER_BLOCK)      // 512
#define BLOCKS_PER_B (NPTS / PTS_PER_BLOCK)          // 64

// Broadcast lane k's float to all lanes via v_readlane (VALU, no LDS pipe).
__device__ __forceinline__ float bcast(float v, int k) {
    return __int_as_float(__builtin_amdgcn_readlane(__float_as_int(v), k));
}

// ---------------------------------------------------------------------------
// Main kernel. Lane k of every wave folds cluster k's record (once per wave,
// ~7% of loop cost) and keeps it in 13 VGPRs:
//   m[9] = sqrt(0.5*log2 e) * diag(1/s) * R^T   (row-major)
//   q[3] = M * center,  cst = constants[b,k]
// weight = cst * exp2(-|M p - q|^2).  Inner loop: per cluster, 13 readlane
// broadcasts + per-point {9 fma, 3 d2, v_exp_f32, acc-fma}. Zero LDS, zero
// VMEM, zero atomics in the loop. Block partial -> ws (no global atomics).
// ---------------------------------------------------------------------------
__global__ __launch_bounds__(BLOCK) void point_loss_kernel(
    const float4* __restrict__ pts,
    const float*  __restrict__ constants,
    const float*  __restrict__ scales,
    const float*  __restrict__ rotations,
    const float*  __restrict__ centers,
    float*        __restrict__ partials)
{
    __shared__ float wave_sums[BLOCK / 64];

    const int tid  = threadIdx.x;
    const int lane = tid & 63;
    const int b    = blockIdx.x / BLOCKS_PER_B;

    // ---- per-lane fold: cluster = lane ----
    float rec[13];
    {
        const int base = b * KCL + lane;
        const float rx = rotations[3 * base + 0];
        const float ry = rotations[3 * base + 1];
        const float rz = rotations[3 * base + 2];
        const float sx = sinf(rx), cx = cosf(rx);
        const float sy = sinf(ry), cy = cosf(ry);
        const float sz = sinf(rz), cz = cosf(rz);

        float R[3][3];
        R[0][0] = cz * cy; R[0][1] = cz * sy * sx - sz * cx; R[0][2] = cz * sy * cx + sz * sx;
        R[1][0] = sz * cy; R[1][1] = sz * sy * sx + cz * cx; R[1][2] = sz * sy * cx - cz * sx;
        R[2][0] = -sy;     R[2][1] = cy * sx;                R[2][2] = cy * cx;

        const float SC = 0.84932184f;  // sqrt(0.5 * log2(e))
        const float inv[3] = { SC / scales[3 * base + 0],
                               SC / scales[3 * base + 1],
                               SC / scales[3 * base + 2] };
        const float c0 = centers[3 * base + 0];
        const float c1 = centers[3 * base + 1];
        const float c2 = centers[3 * base + 2];

        #pragma unroll
        for (int i = 0; i < 3; ++i) {
            const float m0 = R[0][i] * inv[i];
            const float m1 = R[1][i] * inv[i];
            const float m2 = R[2][i] * inv[i];
            rec[i * 3 + 0] = m0;
            rec[i * 3 + 1] = m1;
            rec[i * 3 + 2] = m2;
            rec[9 + i] = m0 * c0 + m1 * c1 + m2 * c2;
        }
        rec[12] = constants[base];
    }

    // ---- point phase: 2 points per thread ----
    const int n0 = (blockIdx.x % BLOCKS_PER_B) * PTS_PER_BLOCK + tid;
    const float4 p0 = pts[b * NPTS + n0];
    const float4 p1 = pts[b * NPTS + n0 + BLOCK];

    float sdf0 = 0.0f, sdf1 = 0.0f;
    #pragma unroll 8
    for (int k = 0; k < KCL; ++k) {
        const float m0 = bcast(rec[0], k);
        const float m1 = bcast(rec[1], k);
        const float m2 = bcast(rec[2], k);
        const float m3 = bcast(rec[3], k);
        const float m4 = bcast(rec[4], k);
        const float m5 = bcast(rec[5], k);
        const float m6 = bcast(rec[6], k);
        const float m7 = bcast(rec[7], k);
        const float m8 = bcast(rec[8], k);
        const float q0 = bcast(rec[9], k);
        const float q1 = bcast(rec[10], k);
        const float q2 = bcast(rec[11], k);
        const float cs = bcast(rec[12], k);

        float vx = fmaf(m0, p0.x, fmaf(m1, p0.y, fmaf(m2, p0.z, -q0)));
        float vy = fmaf(m3, p0.x, fmaf(m4, p0.y, fmaf(m5, p0.z, -q1)));
        float vz = fmaf(m6, p0.x, fmaf(m7, p0.y, fmaf(m8, p0.z, -q2)));
        float d2 = fmaf(vx, vx, fmaf(vy, vy, vz * vz));
        sdf0 = fmaf(cs, __builtin_amdgcn_exp2f(-d2), sdf0);

        vx = fmaf(m0, p1.x, fmaf(m1, p1.y, fmaf(m2, p1.z, -q0)));
        vy = fmaf(m3, p1.x, fmaf(m4, p1.y, fmaf(m5, p1.z, -q1)));
        vz = fmaf(m6, p1.x, fmaf(m7, p1.y, fmaf(m8, p1.z, -q2)));
        d2 = fmaf(vx, vx, fmaf(vy, vy, vz * vz));
        sdf1 = fmaf(cs, __builtin_amdgcn_exp2f(-d2), sdf1);
    }

    // ---- loss terms ----
    const float gt0 = (p0.w > 0.0f) ? 1.0f : 0.0f;
    const float z0  = 100.0f * (sdf0 + 0.07f);
    const float pr0 = 1.0f / (1.0f + __builtin_amdgcn_exp2f(-1.44269504f * z0));
    const float w0  = gt0 + 10.0f * (1.0f - gt0);
    const float d0  = gt0 - pr0;

    const float gt1 = (p1.w > 0.0f) ? 1.0f : 0.0f;
    const float z1  = 100.0f * (sdf1 + 0.07f);
    const float pr1 = 1.0f / (1.0f + __builtin_amdgcn_exp2f(-1.44269504f * z1));
    const float w1  = gt1 + 10.0f * (1.0f - gt1);
    const float d1  = gt1 - pr1;

    float term = w0 * d0 * d0 + w1 * d1 * d1;

    #pragma unroll
    for (int off = 32; off > 0; off >>= 1)
        term += __shfl_down(term, off, 64);

    if ((tid & 63) == 0) wave_sums[tid >> 6] = term;
    __syncthreads();

    if (tid == 0) {
        float s = 0.0f;
        #pragma unroll
        for (int i = 0; i < BLOCK / 64; ++i) s += wave_sums[i];
        partials[blockIdx.x] = s;
    }
}

// ---------------------------------------------------------------------------
// Final reduce: 1 block, 256 threads, sums NBLOCKS=512 partials.
// ---------------------------------------------------------------------------
__global__ __launch_bounds__(256) void reduce_kernel(
    const float* __restrict__ partials,
    float*       __restrict__ out)
{
    __shared__ float wave_sums[4];
    const int tid = threadIdx.x;
    float s = partials[tid] + partials[tid + 256];

    #pragma unroll
    for (int off = 32; off > 0; off >>= 1)
        s += __shfl_down(s, off, 64);

    if ((tid & 63) == 0) wave_sums[tid >> 6] = s;
    __syncthreads();

    if (tid == 0) {
        float t = wave_sums[0] + wave_sums[1] + wave_sums[2] + wave_sums[3];
        out[0] = t * (1.0f / (NBATCH * (float)NPTS));
    }
}

extern "C" void kernel_launch(void* const* d_in, const int* in_sizes, int n_in,
                              void* d_out, int out_size, void* d_ws, size_t ws_size,
                              hipStream_t stream) {
    const float4* pts       = (const float4*)d_in[0];
    const float*  constants = (const float*)d_in[1];
    const float*  scales    = (const float*)d_in[2];
    const float*  rotations = (const float*)d_in[3];
    const float*  centers   = (const float*)d_in[4];
    float* out      = (float*)d_out;
    float* partials = (float*)d_ws;

    point_loss_kernel<<<NBLOCKS, BLOCK, 0, stream>>>(
        pts, constants, scales, rotations, centers, partials);
    reduce_kernel<<<1, 256, 0, stream>>>(partials, out);
}

// Round 6
// 16.199 us; speedup vs baseline: 1.9123x; 1.3662x over previous
//
#include <hip/hip_runtime.h>
#include <math.h>

#define KCL 64
#define NPTS 32768
#define NBATCH 8
#define BLOCK 256
#define PPT 4
#define PTS_PER_BLOCK (BLOCK * PPT)                  // 1024
#define NBLOCKS (NBATCH * NPTS / PTS_PER_BLOCK)      // 256
#define BLOCKS_PER_B (NPTS / PTS_PER_BLOCK)          // 32

// ---------------------------------------------------------------------------
// Quadratic-form record per cluster (12 floats, 3x float4):
//   s(p) = G0 x^2 + G1 y^2 + G2 z^2 + G3 xy + G4 xz + G5 yz
//        + G6 x + G7 y + G8 z + G9
// where, with M = sqrt(0.5*log2 e) * diag(1/s) * R^T, q = M c:
//   A = M^T M, t = M^T q
//   G0..2 = -diag(A), G3..5 = -2*offdiag(A), G6..8 = 2t,
//   G9 = -|q|^2 + log2(-cst)         (constants are always <= 0)
// Then weight = cst*exp(-0.5 dist2) = -exp2(s), sdf = -sum_k exp2(s_k).
// Inner loop per point-cluster: 9 fma + v_exp_f32 + add. 3 ds_read_b128
// wave-uniform broadcasts per cluster (conflict-free).
// PPT=4 halves resident waves vs R3 -> LDS issue pipe no longer dominant.
// ---------------------------------------------------------------------------
__global__ __launch_bounds__(BLOCK) void point_loss_kernel(
    const float4* __restrict__ pts,
    const float*  __restrict__ constants,
    const float*  __restrict__ scales,
    const float*  __restrict__ rotations,
    const float*  __restrict__ centers,
    float*        __restrict__ partials)
{
    __shared__ float4 cl4[KCL][3];
    __shared__ float wave_sums[BLOCK / 64];

    const int tid = threadIdx.x;
    const int b   = blockIdx.x / BLOCKS_PER_B;

    // ---- fold phase: wave 0, lane = cluster ----
    if (tid < KCL) {
        const int base = b * KCL + tid;
        const float rx = rotations[3 * base + 0];
        const float ry = rotations[3 * base + 1];
        const float rz = rotations[3 * base + 2];
        const float sx = sinf(rx), cx = cosf(rx);
        const float sy = sinf(ry), cy = cosf(ry);
        const float sz = sinf(rz), cz = cosf(rz);

        float R[3][3];
        R[0][0] = cz * cy; R[0][1] = cz * sy * sx - sz * cx; R[0][2] = cz * sy * cx + sz * sx;
        R[1][0] = sz * cy; R[1][1] = sz * sy * sx + cz * cx; R[1][2] = sz * sy * cx - cz * sx;
        R[2][0] = -sy;     R[2][1] = cy * sx;                R[2][2] = cy * cx;

        const float SC = 0.84932184f;  // sqrt(0.5 * log2(e))
        const float inv[3] = { SC / scales[3 * base + 0],
                               SC / scales[3 * base + 1],
                               SC / scales[3 * base + 2] };
        const float c0 = centers[3 * base + 0];
        const float c1 = centers[3 * base + 1];
        const float c2 = centers[3 * base + 2];

        // M[i][j] = R[j][i] * inv[i]; q = M c
        float M[3][3], q[3];
        #pragma unroll
        for (int i = 0; i < 3; ++i) {
            M[i][0] = R[0][i] * inv[i];
            M[i][1] = R[1][i] * inv[i];
            M[i][2] = R[2][i] * inv[i];
            q[i] = M[i][0] * c0 + M[i][1] * c1 + M[i][2] * c2;
        }
        // A = M^T M (cols j,l), t = M^T q
        float A[3][3], t[3];
        #pragma unroll
        for (int j = 0; j < 3; ++j) {
            #pragma unroll
            for (int l = 0; l < 3; ++l)
                A[j][l] = M[0][j] * M[0][l] + M[1][j] * M[1][l] + M[2][j] * M[2][l];
            t[j] = M[0][j] * q[0] + M[1][j] * q[1] + M[2][j] * q[2];
        }
        const float cst = constants[base];
        const float G9 = -(q[0]*q[0] + q[1]*q[1] + q[2]*q[2]) + log2f(-cst);

        cl4[tid][0] = make_float4(-A[0][0], -A[1][1], -A[2][2], -2.0f * A[0][1]);
        cl4[tid][1] = make_float4(-2.0f * A[0][2], -2.0f * A[1][2], 2.0f * t[0], 2.0f * t[1]);
        cl4[tid][2] = make_float4(2.0f * t[2], G9, 0.0f, 0.0f);
    }
    __syncthreads();

    // ---- point phase: 4 points per thread ----
    const int n0 = b * NPTS + (blockIdx.x % BLOCKS_PER_B) * PTS_PER_BLOCK + tid;
    float4 p[PPT];
    #pragma unroll
    for (int j = 0; j < PPT; ++j) p[j] = pts[n0 + j * BLOCK];

    // per-point feature vector pieces
    float X[PPT], Y[PPT], Z[PPT], X2[PPT], Y2[PPT], Z2[PPT], XY[PPT], XZ[PPT], YZ[PPT];
    #pragma unroll
    for (int j = 0; j < PPT; ++j) {
        X[j] = p[j].x; Y[j] = p[j].y; Z[j] = p[j].z;
        X2[j] = X[j] * X[j]; Y2[j] = Y[j] * Y[j]; Z2[j] = Z[j] * Z[j];
        XY[j] = X[j] * Y[j]; XZ[j] = X[j] * Z[j]; YZ[j] = Y[j] * Z[j];
    }

    float acc[PPT] = {0.0f, 0.0f, 0.0f, 0.0f};
    #pragma unroll 4
    for (int k = 0; k < KCL; ++k) {
        const float4 A  = cl4[k][0];
        const float4 Bv = cl4[k][1];
        const float4 C  = cl4[k][2];
        #pragma unroll
        for (int j = 0; j < PPT; ++j) {
            float s = fmaf(A.x, X2[j],
                      fmaf(A.y, Y2[j],
                      fmaf(A.z, Z2[j],
                      fmaf(A.w, XY[j],
                      fmaf(Bv.x, XZ[j],
                      fmaf(Bv.y, YZ[j],
                      fmaf(Bv.z, X[j],
                      fmaf(Bv.w, Y[j],
                      fmaf(C.x, Z[j], C.y)))))))));
            acc[j] += __builtin_amdgcn_exp2f(s);
        }
    }

    // ---- loss terms ----
    float term = 0.0f;
    #pragma unroll
    for (int j = 0; j < PPT; ++j) {
        const float sdf = -acc[j];
        const float gt  = (p[j].w > 0.0f) ? 1.0f : 0.0f;
        const float z   = 100.0f * (sdf + 0.07f);
        const float pr  = 1.0f / (1.0f + __builtin_amdgcn_exp2f(-1.44269504f * z));
        const float w   = 10.0f - 9.0f * gt;
        const float d   = gt - pr;
        term = fmaf(w * d, d, term);
    }

    #pragma unroll
    for (int off = 32; off > 0; off >>= 1)
        term += __shfl_down(term, off, 64);

    if ((tid & 63) == 0) wave_sums[tid >> 6] = term;
    __syncthreads();

    if (tid == 0) {
        float s = 0.0f;
        #pragma unroll
        for (int i = 0; i < BLOCK / 64; ++i) s += wave_sums[i];
        partials[blockIdx.x] = s;
    }
}

// ---------------------------------------------------------------------------
// Final reduce: 1 block, 256 threads, sums NBLOCKS=256 partials.
// ---------------------------------------------------------------------------
__global__ __launch_bounds__(256) void reduce_kernel(
    const float* __restrict__ partials,
    float*       __restrict__ out)
{
    __shared__ float wave_sums[4];
    const int tid = threadIdx.x;
    float s = partials[tid];

    #pragma unroll
    for (int off = 32; off > 0; off >>= 1)
        s += __shfl_down(s, off, 64);

    if ((tid & 63) == 0) wave_sums[tid >> 6] = s;
    __syncthreads();

    if (tid == 0) {
        float t = wave_sums[0] + wave_sums[1] + wave_sums[2] + wave_sums[3];
        out[0] = t * (1.0f / (NBATCH * (float)NPTS));
    }
}

extern "C" void kernel_launch(void* const* d_in, const int* in_sizes, int n_in,
                              void* d_out, int out_size, void* d_ws, size_t ws_size,
                              hipStream_t stream) {
    const float4* pts       = (const float4*)d_in[0];
    const float*  constants = (const float*)d_in[1];
    const float*  scales    = (const float*)d_in[2];
    const float*  rotations = (const float*)d_in[3];
    const float*  centers   = (const float*)d_in[4];
    float* out      = (float*)d_out;
    float* partials = (float*)d_ws;

    point_loss_kernel<<<NBLOCKS, BLOCK, 0, stream>>>(
        pts, constants, scales, rotations, centers, partials);
    reduce_kernel<<<1, 256, 0, stream>>>(partials, out);
}